// Round 9
// baseline (18.748 us; speedup 1.0000x reference)
//
#include <hip/hip_runtime.h>
#include <math.h>

// Problem constants from the reference
#define BB 32
#define NN 8
#define TT 52
#define HH 224
#define WW 224
#define PP 100    // 10x10 local grid; point p: slot A = lane p (p<64), slot B = lane p-64
#define NWAVE 13  // waves per block
#define KPT 2     // trajectories (t) per wave: block covers 13*2 = 26 = TT/2
#define HALVES 2  // blocks per (b,n) output

__global__ __launch_bounds__(NWAVE * 64) void mapcoll_fused(
    const float* __restrict__ x,        // (B,N,T,6)
    const float* __restrict__ dmap,     // (B,H,W)
    const float* __restrict__ extent,   // (B,3)
    const float* __restrict__ rfa,      // (B,3,3)
    float* __restrict__ out)            // (B*N), pre-zeroed
{
    const int bn   = blockIdx.x >> 1;   // 0..255
    const int half = blockIdx.x & 1;    // 0..1: which 26 t's
    const int b    = bn >> 3;           // NN == 8
    const int wv   = threadIdx.x >> 6;
    const int lane = threadIdx.x & 63;

    __shared__ float s_part[NWAVE];

    // ---- per-b uniforms (hoisted: constant across this block's 26 t's) ----
    const float lwx = extent[b * 3 + 0];
    const float lwy = extent[b * 3 + 1];
    const float inv_diag = 1.0f / sqrtf(lwx * lwx + lwy * lwy);
    const float r00 = rfa[b*9+0], r01 = rfa[b*9+1], r02 = rfa[b*9+2];
    const float r10 = rfa[b*9+3], r11 = rfa[b*9+4], r12 = rfa[b*9+5];
    const float* __restrict__ map_b = dmap + (size_t)b * (HH * WW);
    // Rigid-motion invariance: |a_p - a_q|^2 = ((i_p-i_q)*sx)^2 + ((j_p-j_q)*sy)^2
    const float sx  = lwx * (1.0f / 9.0f);
    const float sy  = lwy * (1.0f / 9.0f);
    const float sy2 = sy * sy;

    // ---- per-lane footprint geometry (t-independent) ----
    const int iA = lane / 10, jA = lane - iA * 10;
    const int pB = lane + 64;
    const int iB = pB / 10,   jB = pB - iB * 10;
    const float p0A = (-0.5f + (float)iA * (1.0f/9.0f)) * lwx;
    const float p1A = (-0.5f + (float)jA * (1.0f/9.0f)) * lwy;
    const float p0B = (-0.5f + (float)iB * (1.0f/9.0f)) * lwx;
    const float p1B = (-0.5f + (float)jB * (1.0f/9.0f)) * lwy;
    const bool hasB = (lane < PP - 64);   // 36 lanes own a B point

    // ---- phase 1: transform + rasterize + issue all 2*KPT gathers ----
    float vA[KPT], vB[KPT];
    #pragma unroll
    for (int k = 0; k < KPT; ++k) {
        const int m = bn * TT + half * (TT / HALVES) + wv * KPT + k;
        const float posx = x[m * 6 + 0];
        const float posy = x[m * 6 + 1];
        const float yaw  = x[m * 6 + 3];
        const float sn = __sinf(yaw), cs = __cosf(yaw);
        const float axA = p0A * cs - p1A * sn + posx;
        const float ayA = p0A * sn + p1A * cs + posy;
        {
            const float fx = axA * r00 + ayA * r01 + r02;
            const float fy = axA * r10 + ayA * r11 + r12;
            int ix = (int)fx, iy = (int)fy;    // trunc cast, then clip (ref semantics)
            ix = ix < 0 ? 0 : (ix > WW - 1 ? WW - 1 : ix);
            iy = iy < 0 ? 0 : (iy > HH - 1 ? HH - 1 : iy);
            vA[k] = map_b[iy * WW + ix];
        }
        vB[k] = 1.0f;                          // lanes without B point: "free"
        if (hasB) {
            const float axB = p0B * cs - p1B * sn + posx;
            const float ayB = p0B * sn + p1B * cs + posy;
            const float fx = axB * r00 + ayB * r01 + r02;
            const float fy = axB * r10 + ayB * r11 + r12;
            int ix = (int)fx, iy = (int)fy;
            ix = ix < 0 ? 0 : (ix > WW - 1 ? WW - 1 : ix);
            iy = iy < 0 ? 0 : (iy > HH - 1 ? HH - 1 : iy);
            vB[k] = map_b[iy * WW + ix];
        }
    }

    // ---- phase 2: masks + per-row nearest-free-column min ----
    float acc = 0.0f;
    #pragma unroll
    for (int k = 0; k < KPT; ++k) {
        const int clA = (vA[k] == 0.0f) ? 1 : 0;   // offroad==1 <=> drv==0 ({0,1} map)
        const int clB = (vB[k] == 0.0f) ? 1 : 0;
        const unsigned long long cmA = __ballot(clA);
        const unsigned long long cmB = __ballot(clB);
        const int ncoll = __popcll(cmA) + __popcll(cmB);
        if (ncoll == 0 || ncoll == PP) continue;    // overlap false -> contributes 0

        // 10-bit FREE-column mask per grid row (wave-uniform)
        const unsigned long long fA = ~cmA;                           // points 0..63
        const unsigned long long fB = (~cmB) & ((1ull << 36) - 1ull); // points 64..99
        unsigned rows[10], revs[10];
        #pragma unroll
        for (int r = 0; r < 6; ++r) rows[r] = (unsigned)((fA >> (10 * r)) & 0x3FFull);
        rows[6] = (unsigned)(((fA >> 60) | (fB << 4)) & 0x3FFull);
        #pragma unroll
        for (int r = 7; r < 10; ++r) rows[r] = (unsigned)((fB >> (10 * r - 64)) & 0x3FFull);
        #pragma unroll
        for (int r = 0; r < 10; ++r) revs[r] = __brev(rows[r]) >> 22;   // 10-bit reverse

        // Empty row -> marker bit 25 -> d=25 -> 625*sy2 >= 30.8 > max real d2 (~26.9)
        {   // slot A (every lane owns one)
            const int invj = 9 - jA;
            float di = (float)iA * sx;
            float mind2 = 1e30f;
            #pragma unroll
            for (int r = 0; r < 10; ++r) {
                const unsigned t = (rows[r] >> jA) | (revs[r] >> invj) | (1u << 25);
                const unsigned d = __builtin_ctz(t);
                mind2 = fminf(mind2, fmaf(di, di, (float)(d * d) * sy2));
                di -= sx;
            }
            acc += clA ? (1.0f - sqrtf(mind2) * inv_diag) : 0.0f;
        }
        {   // slot B (lanes 0..35); clB==0 elsewhere so result is masked anyway
            const int invj = 9 - jB;
            float di = (float)iB * sx;
            float mind2 = 1e30f;
            #pragma unroll
            for (int r = 0; r < 10; ++r) {
                const unsigned t = (rows[r] >> jB) | (revs[r] >> invj) | (1u << 25);
                const unsigned d = __builtin_ctz(t);
                mind2 = fminf(mind2, fmaf(di, di, (float)(d * d) * sy2));
                di -= sx;
            }
            acc += clB ? (1.0f - sqrtf(mind2) * inv_diag) : 0.0f;
        }
    }

    // ---- wave reduce -> LDS -> block reduce -> one atomic per block ----
    #pragma unroll
    for (int off = 32; off > 0; off >>= 1) acc += __shfl_down(acc, off);
    if (lane == 0) s_part[wv] = acc;
    __syncthreads();
    if (threadIdx.x < 64) {
        float v = (lane < NWAVE) ? s_part[lane] : 0.0f;
        v += __shfl_down(v, 8);
        v += __shfl_down(v, 4);
        v += __shfl_down(v, 2);
        v += __shfl_down(v, 1);
        if (lane == 0) atomicAdd(&out[bn], v);   // 2 atomics per output
    }
}

extern "C" void kernel_launch(void* const* d_in, const int* in_sizes, int n_in,
                              void* d_out, int out_size, void* d_ws, size_t ws_size,
                              hipStream_t stream) {
    const float* x      = (const float*)d_in[0];
    const float* dmap   = (const float*)d_in[1];
    const float* extent = (const float*)d_in[2];
    const float* rfa    = (const float*)d_in[3];
    float* out = (float*)d_out;

    // out receives atomic partials -> must start at zero every call
    hipMemsetAsync(out, 0, (size_t)out_size * sizeof(float), stream);

    mapcoll_fused<<<BB * NN * HALVES, NWAVE * 64, 0, stream>>>(x, dmap, extent, rfa, out);
}

// Round 10
// 13.471 us; speedup vs baseline: 1.3917x; 1.3917x over previous
//
#include <hip/hip_runtime.h>
#include <math.h>

// Problem constants from the reference
#define BB 32
#define NN 8
#define TT 52
#define HH 224
#define WW 224
#define PP 100    // 10x10 local grid; point p: slot A = lane p (p<64), slot B = lane p-64
#define NWAVE 16  // waves per block (1024 threads); block = one (b,n) output

__device__ __forceinline__ float rlane_f(float v, int l) {
    return __int_as_float(__builtin_amdgcn_readlane(__float_as_int(v), l));
}

__global__ __launch_bounds__(NWAVE * 64) void mapcoll_fused(
    const float* __restrict__ x,        // (B,N,T,6)
    const float* __restrict__ dmap,     // (B,H,W)
    const float* __restrict__ extent,   // (B,3)
    const float* __restrict__ rfa,      // (B,3,3)
    float* __restrict__ out)            // (B*N)
{
    const int bn   = blockIdx.x;        // 0..255
    const int b    = bn >> 3;           // NN == 8
    const int lane = threadIdx.x & 63;
    const int wvu  = __builtin_amdgcn_readfirstlane((int)(threadIdx.x >> 6)); // uniform wave id

    __shared__ float s_part[NWAVE];

    // ---- per-b uniforms (blockIdx-derived -> scalar loads) ----
    const float lwx = extent[b * 3 + 0];
    const float lwy = extent[b * 3 + 1];
    const float inv_diag = 1.0f / sqrtf(lwx * lwx + lwy * lwy);
    const float r00 = rfa[b*9+0], r01 = rfa[b*9+1], r02 = rfa[b*9+2];
    const float r10 = rfa[b*9+3], r11 = rfa[b*9+4], r12 = rfa[b*9+5];
    const float* __restrict__ map_b = dmap + (size_t)b * (HH * WW);
    // Rigid-motion invariance: |a_p - a_q|^2 = ((i_p-i_q)*sx)^2 + ((j_p-j_q)*sy)^2
    const float sx  = lwx * (1.0f / 9.0f);
    const float sy  = lwy * (1.0f / 9.0f);
    const float sy2 = sy * sy;

    // ---- lane-parallel prologue: lane t<52 loads pos/yaw, computes sin/cos ----
    float ppx = 0.0f, ppy = 0.0f, psn = 0.0f, pcs = 1.0f;
    if (lane < TT) {
        const int base = bn * TT * 6 + lane * 6;
        const float2 p2 = *reinterpret_cast<const float2*>(x + base);
        ppx = p2.x; ppy = p2.y;
        const float yw = x[base + 3];
        psn = __sinf(yw);
        pcs = __cosf(yw);
    }

    // ---- per-lane footprint geometry (t-independent) ----
    const int iA = lane / 10, jA = lane - iA * 10;
    const int pB = lane + 64;
    const int iB = pB / 10,   jB = pB - iB * 10;
    const float p0A = (-0.5f + (float)iA * (1.0f/9.0f)) * lwx;
    const float p1A = (-0.5f + (float)jA * (1.0f/9.0f)) * lwy;
    const float p0B = (-0.5f + (float)iB * (1.0f/9.0f)) * lwx;
    const float p1B = (-0.5f + (float)jB * (1.0f/9.0f)) * lwy;
    const bool hasB = (lane < PP - 64);   // 36 lanes own a B point

    // t distribution over 16 waves: waves 0..3 -> 4 t's, waves 4..15 -> 3 t's (52 total)
    const int kn = (wvu < 4) ? 4 : 3;
    const int t0 = (wvu < 4) ? (wvu * 4) : (16 + (wvu - 4) * 3);

    // ---- phase 1: transform + rasterize + issue all gathers ----
    float vA[4], vB[4];
    #pragma unroll
    for (int k = 0; k < 4; ++k) {
        vA[k] = 1.0f;                       // "free" for skipped slots
        vB[k] = 1.0f;
        if (k < kn) {                       // wave-uniform guard
            const int t = t0 + k;
            const float posx = rlane_f(ppx, t);
            const float posy = rlane_f(ppy, t);
            const float sn   = rlane_f(psn, t);
            const float cs   = rlane_f(pcs, t);
            const float axA = p0A * cs - p1A * sn + posx;
            const float ayA = p0A * sn + p1A * cs + posy;
            {
                const float fx = axA * r00 + ayA * r01 + r02;
                const float fy = axA * r10 + ayA * r11 + r12;
                int ix = (int)fx, iy = (int)fy;    // trunc cast, then clip (ref semantics)
                ix = ix < 0 ? 0 : (ix > WW - 1 ? WW - 1 : ix);
                iy = iy < 0 ? 0 : (iy > HH - 1 ? HH - 1 : iy);
                vA[k] = map_b[iy * WW + ix];
            }
            if (hasB) {
                const float axB = p0B * cs - p1B * sn + posx;
                const float ayB = p0B * sn + p1B * cs + posy;
                const float fx = axB * r00 + ayB * r01 + r02;
                const float fy = axB * r10 + ayB * r11 + r12;
                int ix = (int)fx, iy = (int)fy;
                ix = ix < 0 ? 0 : (ix > WW - 1 ? WW - 1 : ix);
                iy = iy < 0 ? 0 : (iy > HH - 1 ? HH - 1 : iy);
                vB[k] = map_b[iy * WW + ix];
            }
        }
    }

    // ---- phase 2: masks + per-row nearest-free-column min ----
    float acc = 0.0f;
    #pragma unroll
    for (int k = 0; k < 4; ++k) {
        if (k >= kn) continue;                     // wave-uniform
        const int clA = (vA[k] == 0.0f) ? 1 : 0;   // offroad==1 <=> drv==0 ({0,1} map)
        const int clB = (vB[k] == 0.0f) ? 1 : 0;
        const unsigned long long cmA = __ballot(clA);
        const unsigned long long cmB = __ballot(clB);
        const int ncoll = __popcll(cmA) + __popcll(cmB);
        if (ncoll == 0 || ncoll == PP) continue;   // overlap false -> contributes 0

        // 10-bit FREE-column mask per grid row (wave-uniform -> SALU)
        const unsigned long long fA = ~cmA;                           // points 0..63
        const unsigned long long fB = (~cmB) & ((1ull << 36) - 1ull); // points 64..99
        unsigned rows[10], revs[10];
        #pragma unroll
        for (int r = 0; r < 6; ++r) rows[r] = (unsigned)((fA >> (10 * r)) & 0x3FFull);
        rows[6] = (unsigned)(((fA >> 60) | (fB << 4)) & 0x3FFull);
        #pragma unroll
        for (int r = 7; r < 10; ++r) rows[r] = (unsigned)((fB >> (10 * r - 64)) & 0x3FFull);
        #pragma unroll
        for (int r = 0; r < 10; ++r) revs[r] = __brev(rows[r]) >> 22;   // 10-bit reverse

        // Empty row -> marker bit 25 -> d=25 -> 625*sy2 >= 30.8 > max real d2 (~26.9)
        {   // slot A (every lane owns one)
            const int invj = 9 - jA;
            float di = (float)iA * sx;
            float mind2 = 1e30f;
            #pragma unroll
            for (int r = 0; r < 10; ++r) {
                const unsigned t = (rows[r] >> jA) | (revs[r] >> invj) | (1u << 25);
                const unsigned d = __builtin_ctz(t);
                mind2 = fminf(mind2, fmaf(di, di, (float)(d * d) * sy2));
                di -= sx;
            }
            acc += clA ? (1.0f - sqrtf(mind2) * inv_diag) : 0.0f;
        }
        {   // slot B (lanes 0..35); clB==0 elsewhere so result is masked anyway
            const int invj = 9 - jB;
            float di = (float)iB * sx;
            float mind2 = 1e30f;
            #pragma unroll
            for (int r = 0; r < 10; ++r) {
                const unsigned t = (rows[r] >> jB) | (revs[r] >> invj) | (1u << 25);
                const unsigned d = __builtin_ctz(t);
                mind2 = fminf(mind2, fmaf(di, di, (float)(d * d) * sy2));
                di -= sx;
            }
            acc += clB ? (1.0f - sqrtf(mind2) * inv_diag) : 0.0f;
        }
    }

    // ---- wave reduce -> LDS -> block reduce -> single store ----
    #pragma unroll
    for (int off = 32; off > 0; off >>= 1) acc += __shfl_down(acc, off);
    if (lane == 0) s_part[wvu] = acc;
    __syncthreads();
    if (threadIdx.x < 64) {
        float v = (lane < NWAVE) ? s_part[lane] : 0.0f;
        v += __shfl_down(v, 8);
        v += __shfl_down(v, 4);
        v += __shfl_down(v, 2);
        v += __shfl_down(v, 1);
        if (lane == 0) out[bn] = v;   // every output written -> no memset needed
    }
}

extern "C" void kernel_launch(void* const* d_in, const int* in_sizes, int n_in,
                              void* d_out, int out_size, void* d_ws, size_t ws_size,
                              hipStream_t stream) {
    const float* x      = (const float*)d_in[0];
    const float* dmap   = (const float*)d_in[1];
    const float* extent = (const float*)d_in[2];
    const float* rfa    = (const float*)d_in[3];
    float* out = (float*)d_out;

    mapcoll_fused<<<BB * NN, NWAVE * 64, 0, stream>>>(x, dmap, extent, rfa, out);
}